// Round 3
// baseline (1197.227 us; speedup 1.0000x reference)
//
#include <hip/hip_runtime.h>
#include <hip/hip_bf16.h>
#include <stdint.h>

typedef __bf16 bf16x8 __attribute__((ext_vector_type(8)));
typedef float f32x4 __attribute__((ext_vector_type(4)));
typedef unsigned short u16x4 __attribute__((ext_vector_type(4)));

__device__ __forceinline__ unsigned short f2bf(float f) {
    union { float f; uint32_t u; } v; v.f = f;
    uint32_t u = v.u;
    return (unsigned short)((u + 0x7fffu + ((u >> 16) & 1u)) >> 16);
}

// ---- prep: f32 -> bf16 feature conversion (x4); tail zeroes the pad row ----
__global__ __launch_bounds__(256) void prep_x(const f32x4* __restrict__ x,
                                              u16x4* __restrict__ xb, int n4, int n4tot) {
    int t = blockIdx.x * 256 + threadIdx.x;
    if (t < n4) {
        f32x4 v = x[t];
        u16x4 o;
        o.x = f2bf(v.x); o.y = f2bf(v.y); o.z = f2bf(v.z); o.w = f2bf(v.w);
        xb[t] = o;
    } else if (t < n4tot) {
        u16x4 z = {0, 0, 0, 0};
        xb[t] = z;                       // zero row at index N (masked-gather target)
    }
}

// ---- zero one 64-ch row (pad row of the hidden buffer) ----
__global__ void zero_row(unsigned short* __restrict__ p, long off) {
    p[off + threadIdx.x] = 0;
}

// ---- prep: W[k][ci][co] f32 -> Wt[k][co][ci] bf16; blocks k>=K write zeros ----
__global__ __launch_bounds__(256) void prep_w(const float* __restrict__ W,
                                              unsigned short* __restrict__ Wt, int K) {
    int k = blockIdx.x;
    unsigned short* Wtk = Wt + (size_t)k * 4096;
    if (k >= K) {
        for (int j = threadIdx.x; j < 4096; j += 256) Wtk[j] = 0;
        return;
    }
    const float* Wk = W + (size_t)k * 4096;
    for (int j = threadIdx.x; j < 4096; j += 256) {
        int ci = j >> 6, co = j & 63;
        Wtk[co * 64 + ci] = f2bf(Wk[j]);
    }
}

// ---- detect mask element width: 0=int32, 1=bytes(bool), 2=float32 ----
__global__ void detect_mask(const unsigned int* __restrict__ m, int* __restrict__ flag) {
    __shared__ int s_not_int, s_not_f32;
    if (threadIdx.x == 0) { s_not_int = 0; s_not_f32 = 0; }
    __syncthreads();
    unsigned int w = m[threadIdx.x];          // first 4KB: safe for all widths
    if (w > 1u) s_not_int = 1;                // benign race
    if (w != 0u && w != 0x3f800000u) s_not_f32 = 1;
    __syncthreads();
    if (threadIdx.x == 0) *flag = s_not_int ? (s_not_f32 ? 1 : 2) : 0;
}

// ---- main sparse conv: branchless gather, SW-pipelined PF deep, MFMA ----
// MODE 0: out = bf16 relu(acc + bias)   (hidden layer)
// MODE 1: out = f32  acc + bias + resid (final layer)
template <int MODE>
__global__ __launch_bounds__(256, 1) void conv_mfma(
    const unsigned short* __restrict__ xb,   // [N+1][64] bf16 (row N = zeros)
    const int* __restrict__ nbr,             // [N][K]
    const void* __restrict__ maskp,
    const int* __restrict__ flagp,
    const unsigned short* __restrict__ Wt,   // [28][64(co)][64(ci)] bf16 (k=27 zeroed)
    const float* __restrict__ bias,          // [64]
    const float* __restrict__ resid,         // [N][64] f32 (MODE 1)
    void* __restrict__ outp,
    int N, int K)
{
    constexpr int KP = 28;   // padded K (Wt[27] = 0)
    constexpr int PF = 10;   // software-pipeline depth (gathers in flight)

    const int tid = threadIdx.x;
    const int w = tid >> 6;        // wave 0..3
    const int l = tid & 63;
    const int lr = l & 15;         // fragment row/col index
    const int lh = l >> 4;         // 0..3 k-slice group
    const int base = blockIdx.x * 64;
    int i = base + w * 16 + lr;    // this lane's gathered A-row
    if (i >= N) i = N - 1;         // clamp for nbr/mask reads; stores re-guard

    // ---- mask bits (uniform branch on detected dtype) ----
    unsigned int mbits = 0;
    {
        const int flag = *flagp;
        long moff = (long)i * K;
        if (flag == 1) {
            const unsigned char* mp = (const unsigned char*)maskp + moff;
#pragma unroll
            for (int k = 0; k < 27; ++k) mbits |= (mp[k] ? 1u : 0u) << k;
        } else if (flag == 0) {
            const int* mp = (const int*)maskp + moff;
#pragma unroll
            for (int k = 0; k < 27; ++k) mbits |= (mp[k] ? 1u : 0u) << k;
        } else {
            const float* mp = (const float*)maskp + moff;
#pragma unroll
            for (int k = 0; k < 27; ++k) mbits |= ((mp[k] != 0.f) ? 1u : 0u) << k;
        }
    }

    // ---- branchless per-k byte offsets (masked -> zero row N) ----
    unsigned off[KP];
    {
        const int* nrow = nbr + (long)i * K;
#pragma unroll
        for (int k = 0; k < 27; ++k) {
            unsigned row = ((mbits >> k) & 1u) ? (unsigned)nrow[k] : (unsigned)N;
            off[k] = row * 128u + (unsigned)(lh << 4);   // 128 B per row
        }
        off[27] = (unsigned)N * 128u + (unsigned)(lh << 4);
    }

    const char* xB = (const char*)xb;

    // ---- prologue: fill the pipeline ----
    bf16x8 fa[PF], fb[PF];
#pragma unroll
    for (int k = 0; k < PF; ++k) {
        fa[k] = *(const bf16x8*)(xB + off[k]);        // ci 8*lh..8*lh+7
        fb[k] = *(const bf16x8*)(xB + off[k] + 64);   // ci 32+8*lh..
    }

    f32x4 acc[4] = {};

    // ---- main loop: consume slot k%PF, refill with k+PF (static indices) ----
#pragma unroll
    for (int k = 0; k < KP; ++k) {
        bf16x8 a0 = fa[k % PF];
        bf16x8 a1 = fb[k % PF];
        if (k + PF < KP) {
            fa[k % PF] = *(const bf16x8*)(xB + off[k + PF]);
            fb[k % PF] = *(const bf16x8*)(xB + off[k + PF] + 64);
        }
        const unsigned short* wk = Wt + ((long)k << 12) + lr * 64 + (lh << 3);
#pragma unroll
        for (int cb = 0; cb < 4; ++cb) {
            bf16x8 b0 = *(const bf16x8*)(wk + cb * 1024);
            bf16x8 b1 = *(const bf16x8*)(wk + cb * 1024 + 32);
            acc[cb] = __builtin_amdgcn_mfma_f32_16x16x32_bf16(a0, b0, acc[cb], 0, 0, 0);
            acc[cb] = __builtin_amdgcn_mfma_f32_16x16x32_bf16(a1, b1, acc[cb], 0, 0, 0);
        }
    }

    // ---- epilogue: D row = 4*lh + r (within wave tile), col = cb*16 + lr ----
#pragma unroll
    for (int cb = 0; cb < 4; ++cb) {
        int col = cb * 16 + lr;
        float bv = bias[col];
#pragma unroll
        for (int r = 0; r < 4; ++r) {
            int orow = base + w * 16 + lh * 4 + r;
            if (orow < N) {
                long o = (long)orow * 64 + col;
                float v = acc[cb][r] + bv;
                if (MODE == 0) {
                    v = fmaxf(v, 0.f);
                    ((unsigned short*)outp)[o] = f2bf(v);
                } else {
                    ((float*)outp)[o] = v + resid[o];
                }
            }
        }
    }
}

static inline size_t align256(size_t x) { return (x + 255) & ~(size_t)255; }

extern "C" void kernel_launch(void* const* d_in, const int* in_sizes, int n_in,
                              void* d_out, int out_size, void* d_ws, size_t ws_size,
                              hipStream_t stream) {
    const float* x    = (const float*)d_in[0];
    const int*   nbr  = (const int*)d_in[1];
    const void*  mask = d_in[2];
    const float* W0   = (const float*)d_in[3];
    const float* b0   = (const float*)d_in[4];
    const float* W1   = (const float*)d_in[5];
    const float* b1   = (const float*)d_in[6];

    const int NC = in_sizes[0];      // N*64
    const int N  = NC / 64;
    const int K  = in_sizes[1] / N;  // 27
    const int KP = 28;               // padded K for the unrolled kernel

    char* ws = (char*)d_ws;
    size_t xb_bytes = (size_t)(NC + 64) * 2;   // +1 zero row
    size_t wt_bytes = (size_t)KP * 64 * 64 * 2;
    size_t xb_off   = 0;
    size_t hb_off   = xb_off + align256(xb_bytes);
    size_t wt0_off  = hb_off + align256(xb_bytes);
    size_t wt1_off  = wt0_off + align256(wt_bytes);
    size_t flag_off = wt1_off + align256(wt_bytes);

    unsigned short* xb  = (unsigned short*)(ws + xb_off);
    unsigned short* hb  = (unsigned short*)(ws + hb_off);
    unsigned short* wt0 = (unsigned short*)(ws + wt0_off);
    unsigned short* wt1 = (unsigned short*)(ws + wt1_off);
    int* flag           = (int*)(ws + flag_off);

    int n4 = NC / 4;
    int n4tot = n4 + 16;             // + zero pad row (16 u16x4 = 64 ch)
    prep_x<<<(n4tot + 255) / 256, 256, 0, stream>>>((const f32x4*)x, (u16x4*)xb, n4, n4tot);
    zero_row<<<1, 64, 0, stream>>>(hb, (long)NC);
    prep_w<<<KP, 256, 0, stream>>>(W0, wt0, K);
    prep_w<<<KP, 256, 0, stream>>>(W1, wt1, K);
    detect_mask<<<1, 1024, 0, stream>>>((const unsigned int*)mask, flag);

    int nblocks = (N + 63) / 64;
    conv_mfma<0><<<nblocks, 256, 0, stream>>>(xb, nbr, mask, flag, wt0, b0, nullptr, hb, N, K);
    conv_mfma<1><<<nblocks, 256, 0, stream>>>(hb, nbr, mask, flag, wt1, b1, x, d_out, N, K);
}

// Round 4
// 437.740 us; speedup vs baseline: 2.7350x; 2.7350x over previous
//
#include <hip/hip_runtime.h>
#include <hip/hip_bf16.h>
#include <stdint.h>

typedef __bf16 bf16x8 __attribute__((ext_vector_type(8)));
typedef float f32x16 __attribute__((ext_vector_type(16)));
typedef float f32x4 __attribute__((ext_vector_type(4)));
typedef unsigned short u16x4 __attribute__((ext_vector_type(4)));

__device__ __forceinline__ unsigned short f2bf(float f) {
    union { float f; uint32_t u; } v; v.f = f;
    uint32_t u = v.u;
    return (unsigned short)((u + 0x7fffu + ((u >> 16) & 1u)) >> 16);
}

// ---- prep: f32 -> bf16 feature conversion (x4); tail zeroes the pad row ----
__global__ __launch_bounds__(256) void prep_x(const f32x4* __restrict__ x,
                                              u16x4* __restrict__ xb, int n4, int n4tot) {
    int t = blockIdx.x * 256 + threadIdx.x;
    if (t < n4) {
        f32x4 v = x[t];
        u16x4 o;
        o.x = f2bf(v.x); o.y = f2bf(v.y); o.z = f2bf(v.z); o.w = f2bf(v.w);
        xb[t] = o;
    } else if (t < n4tot) {
        u16x4 z = {0, 0, 0, 0};
        xb[t] = z;                       // zero row at index N (masked-gather target)
    }
}

// ---- zero one 64-ch row (pad row of the hidden buffer) ----
__global__ void zero_row(unsigned short* __restrict__ p, long off) {
    p[off + threadIdx.x] = 0;
}

// ---- prep: W[k][ci][co] f32 -> Wt[k] XOR-swizzled [co][ci^((co&7)<<3)] bf16 ----
// Swizzle baked into GLOBAL layout so a linear global_load_lds copy lands the
// bank-conflict-free LDS image (rule: swizzle source + read, never the dest).
__global__ __launch_bounds__(256) void prep_w(const float* __restrict__ W,
                                              unsigned short* __restrict__ Wt, int K) {
    int k = blockIdx.x;
    unsigned short* Wtk = Wt + (size_t)k * 4096;
    const float* Wk = W + (size_t)k * 4096;
    for (int j = threadIdx.x; j < 4096; j += 256) {
        int ci = j >> 6, co = j & 63;                    // src j = ci*64 + co
        int dst = co * 64 + (ci ^ ((co & 7) << 3));      // XOR-swizzled
        Wtk[dst] = (k < K) ? f2bf(Wk[j]) : (unsigned short)0;
    }
}

// ---- detect mask element width: 0=int32, 1=bytes(bool), 2=float32 ----
__global__ void detect_mask(const unsigned int* __restrict__ m, int* __restrict__ flag) {
    __shared__ int s_not_int, s_not_f32;
    if (threadIdx.x == 0) { s_not_int = 0; s_not_f32 = 0; }
    __syncthreads();
    unsigned int w = m[threadIdx.x];          // first 4KB: safe for all widths
    if (w > 1u) s_not_int = 1;                // benign race
    if (w != 0u && w != 0x3f800000u) s_not_f32 = 1;
    __syncthreads();
    if (threadIdx.x == 0) *flag = s_not_int ? (s_not_f32 ? 1 : 2) : 0;
}

// ---- asm 16B gather load: dest regs filled asynchronously (vmcnt domain) ----
template <int IOFF>
__device__ __forceinline__ bf16x8 gl16(const unsigned short* base, unsigned voff) {
    bf16x8 r;
    asm volatile("global_load_dwordx4 %0, %1, %2 offset:%c3"
                 : "=v"(r) : "v"(voff), "s"(base), "i"(IOFF));
    return r;
}

struct Slot { bf16x8 f[8]; };   // [rt*4+ks]: 2 row-tiles x 4 k-slices

// counted wait that TIES the slot's registers: MFMAs consuming them cannot be
// hoisted above this wait (they now depend on its outputs).
template <int N>
__device__ __forceinline__ void waitv(Slot& s) {
    asm volatile("s_waitcnt vmcnt(%c8)"
                 : "+v"(s.f[0]), "+v"(s.f[1]), "+v"(s.f[2]), "+v"(s.f[3]),
                   "+v"(s.f[4]), "+v"(s.f[5]), "+v"(s.f[6]), "+v"(s.f[7])
                 : "i"(N));
    __builtin_amdgcn_sched_barrier(0);
}

__device__ __forceinline__ void gload_lds16(const unsigned short* g, unsigned short* l) {
    __builtin_amdgcn_global_load_lds(
        (const __attribute__((address_space(1))) void*)(const void*)g,
        (__attribute__((address_space(3))) void*)(void*)l, 16, 0, 0);
}

// ---- main sparse conv ----
// block = 256 rows (4 waves x 64 rows), 32x32x16 MFMA, W double-buffered in LDS
// (7 k-slices per phase, staged one phase ahead; counted vmcnt keeps the gather
// pipeline live across phase boundaries).
// MODE 0: out = bf16 relu(acc + bias)   (hidden layer)
// MODE 1: out = f32  acc + bias + resid (final layer)
template <int MODE>
__global__ __launch_bounds__(256, 1) void conv_mfma(
    const unsigned short* __restrict__ xb,   // [N+1][64] bf16 (row N = zeros)
    const int* __restrict__ nbr,             // [N][K]
    const void* __restrict__ maskp,
    const int* __restrict__ flagp,
    const unsigned short* __restrict__ Wt,   // [28][4096] bf16, XOR-swizzled
    const float* __restrict__ bias,          // [64]
    const float* __restrict__ resid,         // [N][64] f32 (MODE 1)
    void* __restrict__ outp,
    int N, int K)
{
    __shared__ unsigned short Wlds[2][28672];   // 2 x 7 slices x 4096 = 112 KB

    const int tid = threadIdx.x;
    const int wv  = tid >> 6;
    const int l   = tid & 63;
    const int ln  = l & 31;          // MFMA row/col lane index
    const int hf  = l >> 5;          // k-half group
    const unsigned hf16 = (unsigned)(hf << 4);
    const int base = blockIdx.x * 256 + wv * 64;

    int r0 = base + ln, r1 = r0 + 32;
    int r0c = r0 < N ? r0 : N - 1;
    int r1c = r1 < N ? r1 : N - 1;

    // ---- mask bits for both rows (uniform branch on detected dtype) ----
    const int flag = *flagp;
    unsigned mb0 = 0, mb1 = 0;
    {
        long o0 = (long)r0c * K, o1 = (long)r1c * K;
        if (flag == 1) {
            const unsigned char* mp = (const unsigned char*)maskp;
#pragma unroll
            for (int k = 0; k < 27; ++k) {
                mb0 |= (mp[o0 + k] ? 1u : 0u) << k;
                mb1 |= (mp[o1 + k] ? 1u : 0u) << k;
            }
        } else if (flag == 0) {
            const int* mp = (const int*)maskp;
#pragma unroll
            for (int k = 0; k < 27; ++k) {
                mb0 |= (mp[o0 + k] ? 1u : 0u) << k;
                mb1 |= (mp[o1 + k] ? 1u : 0u) << k;
            }
        } else {
            const float* mp = (const float*)maskp;
#pragma unroll
            for (int k = 0; k < 27; ++k) {
                mb0 |= ((mp[o0 + k] != 0.f) ? 1u : 0u) << k;
                mb1 |= ((mp[o1 + k] != 0.f) ? 1u : 0u) << k;
            }
        }
    }

    // ---- branchless per-k byte offsets (masked -> zero row N) ----
    unsigned offA[28], offB[28];
    {
        const int* n0 = nbr + (long)r0c * K;
        const int* n1 = nbr + (long)r1c * K;
#pragma unroll
        for (int k = 0; k < 27; ++k) {
            unsigned g0 = ((mb0 >> k) & 1u) ? (unsigned)n0[k] : (unsigned)N;
            unsigned g1 = ((mb1 >> k) & 1u) ? (unsigned)n1[k] : (unsigned)N;
            offA[k] = g0 * 128u + hf16;
            offB[k] = g1 * 128u + hf16;
        }
        offA[27] = (unsigned)N * 128u + hf16;
        offB[27] = offA[27];
    }

    // ---- per-lane LDS B-frag offsets (u16 units), XOR-swizzled ----
    const int xrr = (ln & 7) << 3;
    int xks[4];
#pragma unroll
    for (int ks = 0; ks < 4; ++ks) xks[ks] = (ks * 16 + hf * 8) ^ xrr;
    const int fb0 = ln * 64;           // col-tile 0 row base
    const int fb1 = fb0 + 2048;        // col-tile 1 (+32 rows * 64)

    f32x16 acc00 = {}, acc01 = {}, acc10 = {}, acc11 = {};
    Slot pipe[4];

#define STAGE(P) do { \
    const unsigned short* _src = Wt + (P) * 28672 + wv * 7168 + l * 8; \
    unsigned short* _dst = &Wlds[(P) & 1][wv * 7168]; \
    _Pragma("unroll") \
    for (int _r = 0; _r < 14; ++_r) \
        gload_lds16(_src + _r * 512, _dst + _r * 512); \
    asm volatile("" ::: "memory"); \
} while (0)

#define REFILL(S) do { \
    Slot& _sl = pipe[(S) & 3]; \
    _sl.f[0] = gl16<0 >(xb, offA[S]); _sl.f[1] = gl16<32>(xb, offA[S]); \
    _sl.f[2] = gl16<64>(xb, offA[S]); _sl.f[3] = gl16<96>(xb, offA[S]); \
    _sl.f[4] = gl16<0 >(xb, offB[S]); _sl.f[5] = gl16<32>(xb, offB[S]); \
    _sl.f[6] = gl16<64>(xb, offB[S]); _sl.f[7] = gl16<96>(xb, offB[S]); \
} while (0)

#define COMPUTE(GK) do { \
    const unsigned short* _wl = &Wlds[((GK) / 7) & 1][((GK) % 7) * 4096]; \
    Slot& _sl = pipe[(GK) & 3]; \
    _Pragma("unroll") \
    for (int ks = 0; ks < 4; ++ks) { \
        bf16x8 _b0 = *(const bf16x8*)(_wl + fb0 + xks[ks]); \
        bf16x8 _b1 = *(const bf16x8*)(_wl + fb1 + xks[ks]); \
        acc00 = __builtin_amdgcn_mfma_f32_32x32x16_bf16(_sl.f[ks],     _b0, acc00, 0, 0, 0); \
        acc01 = __builtin_amdgcn_mfma_f32_32x32x16_bf16(_sl.f[ks],     _b1, acc01, 0, 0, 0); \
        acc10 = __builtin_amdgcn_mfma_f32_32x32x16_bf16(_sl.f[4 + ks], _b0, acc10, 0, 0, 0); \
        acc11 = __builtin_amdgcn_mfma_f32_32x32x16_bf16(_sl.f[4 + ks], _b1, acc11, 0, 0, 0); \
    } \
} while (0)

#define PHASE_ENTRY() do { \
    asm volatile("s_waitcnt vmcnt(56)" ::: "memory"); \
    __builtin_amdgcn_sched_barrier(0); \
    __builtin_amdgcn_s_barrier(); \
    __builtin_amdgcn_sched_barrier(0); \
} while (0)

#define ITER_S(GK, P, NW) do { STAGE(P); REFILL((GK) + 3); waitv<NW>(pipe[(GK) & 3]); COMPUTE(GK); } while (0)
#define ITER_R(GK, NW)    do { REFILL((GK) + 3); waitv<NW>(pipe[(GK) & 3]); COMPUTE(GK); } while (0)
#define ITER_N(GK, NW)    do { waitv<NW>(pipe[(GK) & 3]); COMPUTE(GK); } while (0)

    // ---- prologue: stage phase 0, fill 3 gather slots ----
    STAGE(0);
    REFILL(0); REFILL(1); REFILL(2);
    asm volatile("s_waitcnt vmcnt(24)" ::: "memory");   // stage0 done; gathers fly
    __builtin_amdgcn_sched_barrier(0);
    __builtin_amdgcn_s_barrier();
    __builtin_amdgcn_sched_barrier(0);

    // ---- phase 0 (k 0..6, buf 0) ----
    ITER_S(0, 1, 38);
    ITER_R(1, 38); ITER_R(2, 38);
    ITER_R(3, 24); ITER_R(4, 24); ITER_R(5, 24); ITER_R(6, 24);
    PHASE_ENTRY();
    // ---- phase 1 (k 7..13, buf 1) ----
    ITER_S(7, 2, 38);
    ITER_R(8, 38); ITER_R(9, 38);
    ITER_R(10, 24); ITER_R(11, 24); ITER_R(12, 24); ITER_R(13, 24);
    PHASE_ENTRY();
    // ---- phase 2 (k 14..20, buf 0) ----
    ITER_S(14, 3, 38);
    ITER_R(15, 38); ITER_R(16, 38);
    ITER_R(17, 24); ITER_R(18, 24); ITER_R(19, 24); ITER_R(20, 24);
    PHASE_ENTRY();
    // ---- phase 3 (k 21..27, buf 1; k=27 is the zero pad slice) ----
    ITER_R(21, 24); ITER_R(22, 24); ITER_R(23, 24); ITER_R(24, 24);
    ITER_N(25, 16); ITER_N(26, 8); ITER_N(27, 0);

    // ---- epilogue: D col = ct*32+ln, row = rt*32 + (rg&3) + 8*(rg>>2) + 4*hf ----
    float bv0 = bias[ln], bv1 = bias[32 + ln];

#define EPI(ACC, RT, CT, BV) do { \
    _Pragma("unroll") \
    for (int rg = 0; rg < 16; ++rg) { \
        int row = base + (RT) * 32 + (rg & 3) + 8 * (rg >> 2) + 4 * hf; \
        if (row < N) { \
            long o = (long)row * 64 + (CT) * 32 + ln; \
            float v = ACC[rg] + (BV); \
            if (MODE == 0) ((unsigned short*)outp)[o] = f2bf(v > 0.f ? v : 0.f); \
            else           ((float*)outp)[o] = v + resid[o]; \
        } \
    } \
} while (0)

    EPI(acc00, 0, 0, bv0); EPI(acc01, 0, 1, bv1);
    EPI(acc10, 1, 0, bv0); EPI(acc11, 1, 1, bv1);

#undef STAGE
#undef REFILL
#undef COMPUTE
#undef PHASE_ENTRY
#undef ITER_S
#undef ITER_R
#undef ITER_N
#undef EPI
}

static inline size_t align256(size_t x) { return (x + 255) & ~(size_t)255; }

extern "C" void kernel_launch(void* const* d_in, const int* in_sizes, int n_in,
                              void* d_out, int out_size, void* d_ws, size_t ws_size,
                              hipStream_t stream) {
    const float* x    = (const float*)d_in[0];
    const int*   nbr  = (const int*)d_in[1];
    const void*  mask = d_in[2];
    const float* W0   = (const float*)d_in[3];
    const float* b0   = (const float*)d_in[4];
    const float* W1   = (const float*)d_in[5];
    const float* b1   = (const float*)d_in[6];

    const int NC = in_sizes[0];      // N*64
    const int N  = NC / 64;
    const int K  = in_sizes[1] / N;  // 27
    const int KP = 28;               // padded K (k=27 slice zeroed)

    char* ws = (char*)d_ws;
    size_t xb_bytes = (size_t)(NC + 64) * 2;   // +1 zero row
    size_t wt_bytes = (size_t)KP * 4096 * 2;
    size_t xb_off   = 0;
    size_t hb_off   = xb_off + align256(xb_bytes);
    size_t wt0_off  = hb_off + align256(xb_bytes);
    size_t wt1_off  = wt0_off + align256(wt_bytes);
    size_t flag_off = wt1_off + align256(wt_bytes);

    unsigned short* xb  = (unsigned short*)(ws + xb_off);
    unsigned short* hb  = (unsigned short*)(ws + hb_off);
    unsigned short* wt0 = (unsigned short*)(ws + wt0_off);
    unsigned short* wt1 = (unsigned short*)(ws + wt1_off);
    int* flag           = (int*)(ws + flag_off);

    int n4 = NC / 4;
    int n4tot = n4 + 16;             // + zero pad row (16 u16x4 = 64 ch)
    prep_x<<<(n4tot + 255) / 256, 256, 0, stream>>>((const f32x4*)x, (u16x4*)xb, n4, n4tot);
    zero_row<<<1, 64, 0, stream>>>(hb, (long)NC);
    prep_w<<<KP, 256, 0, stream>>>(W0, wt0, K);
    prep_w<<<KP, 256, 0, stream>>>(W1, wt1, K);
    detect_mask<<<1, 1024, 0, stream>>>((const unsigned int*)mask, flag);

    int nblocks = (N + 255) / 256;
    conv_mfma<0><<<nblocks, 256, 0, stream>>>(xb, nbr, mask, flag, wt0, b0, nullptr, hb, N, K);
    conv_mfma<1><<<nblocks, 256, 0, stream>>>(hb, nbr, mask, flag, wt1, b1, x, d_out, N, K);
}

// Round 5
// 369.347 us; speedup vs baseline: 3.2415x; 1.1852x over previous
//
#include <hip/hip_runtime.h>
#include <hip/hip_bf16.h>
#include <stdint.h>

typedef __bf16 bf16x8 __attribute__((ext_vector_type(8)));
typedef __bf16 bf16x4 __attribute__((ext_vector_type(4)));
typedef float f32x4 __attribute__((ext_vector_type(4)));
typedef unsigned short u16x4 __attribute__((ext_vector_type(4)));

__device__ __forceinline__ unsigned short f2bf(float f) {
    union { float f; uint32_t u; } v; v.f = f;
    uint32_t u = v.u;
    return (unsigned short)((u + 0x7fffu + ((u >> 16) & 1u)) >> 16);
}

// ---- prep: f32 -> bf16 feature conversion (x4); tail zeroes the pad row ----
__global__ __launch_bounds__(256) void prep_x(const f32x4* __restrict__ x,
                                              u16x4* __restrict__ xb, int n4, int n4tot) {
    int t = blockIdx.x * 256 + threadIdx.x;
    if (t < n4) {
        f32x4 v = x[t];
        u16x4 o;
        o.x = f2bf(v.x); o.y = f2bf(v.y); o.z = f2bf(v.z); o.w = f2bf(v.w);
        xb[t] = o;
    } else if (t < n4tot) {
        u16x4 z = {0, 0, 0, 0};
        xb[t] = z;                       // zero row at index N (masked-gather target)
    }
}

// ---- zero one 64-ch row (pad row of the hidden buffer) ----
__global__ void zero_row(unsigned short* __restrict__ p, long off) {
    p[off + threadIdx.x] = 0;
}

// ---- prep: W[k][ci][co] f32 -> Wt[k][co][ci] bf16, rows PADDED to 68 u16 ----
// 68-u16 (136B) row stride => ds_read_b64 B-fragment reads are bank-conflict-free.
__global__ __launch_bounds__(256) void prep_w(const float* __restrict__ W,
                                              unsigned short* __restrict__ Wt, int K) {
    int k = blockIdx.x;
    unsigned short* Wtk = Wt + (size_t)k * 4352;      // 64 rows * 68
    const float* Wk = W + (size_t)k * 4096;
    for (int j = threadIdx.x; j < 4352; j += 256) {
        int co = j / 68, ci = j % 68;
        unsigned short v = 0;
        if (k < K && ci < 64) v = f2bf(Wk[ci * 64 + co]);   // W[k][ci][co]
        Wtk[j] = v;
    }
}

// ---- detect mask element width: 0=int32, 1=bytes(bool), 2=float32 ----
__global__ void detect_mask(const unsigned int* __restrict__ m, int* __restrict__ flag) {
    __shared__ int s_not_int, s_not_f32;
    if (threadIdx.x == 0) { s_not_int = 0; s_not_f32 = 0; }
    __syncthreads();
    unsigned int w = m[threadIdx.x];          // first 4KB: safe for all widths
    if (w > 1u) s_not_int = 1;                // benign race
    if (w != 0u && w != 0x3f800000u) s_not_f32 = 1;
    __syncthreads();
    if (threadIdx.x == 0) *flag = s_not_int ? (s_not_f32 ? 1 : 2) : 0;
}

// ---- asm 16B gather load (async; counted vmcnt domain) ----
template <int IOFF>
__device__ __forceinline__ bf16x8 gl16(const unsigned short* base, unsigned voff) {
    bf16x8 r;
    asm volatile("global_load_dwordx4 %0, %1, %2 offset:%c3"
                 : "=v"(r) : "v"(voff), "s"(base), "i"(IOFF));
    return r;
}

struct Slot { bf16x8 f[4]; };   // [tile0 ks0, tile0 ks1, tile1 ks0, tile1 ks1]

// counted wait tying the slot registers: consuming MFMAs can't be hoisted above.
template <int NW>
__device__ __forceinline__ void waitv(Slot& s) {
    asm volatile("s_waitcnt vmcnt(%c4)"
                 : "+v"(s.f[0]), "+v"(s.f[1]), "+v"(s.f[2]), "+v"(s.f[3])
                 : "i"(NW));
    __builtin_amdgcn_sched_barrier(0);
}

__device__ __forceinline__ void gload_lds16(const unsigned short* g, unsigned short* l) {
    __builtin_amdgcn_global_load_lds(
        (const __attribute__((address_space(1))) void*)(const void*)g,
        (__attribute__((address_space(3))) void*)(void*)l, 16, 0, 0);
}

// ---- LDS b64-pair load of a B fragment (8B-aligned; avoids b128 alignment) ----
__device__ __forceinline__ bf16x8 ldb(const unsigned short* p) {
    bf16x4 lo = *(const bf16x4*)p;
    bf16x4 hi = *(const bf16x4*)(p + 4);
    return __builtin_shufflevector(lo, hi, 0, 1, 2, 3, 4, 5, 6, 7);
}

// ---- main sparse conv ----
// 4 waves x 32 rows = 128 rows/block, mfma 16x16x32, A gathered straight into
// fragments (16 rows x 4-lane-coalesced 64B per inst), W staged in LDS with
// 68-u16 padded rows. Counted vmcnt keeps gathers + stages in flight.
// MODE 0: out = bf16 relu(acc + bias)   (hidden layer)
// MODE 1: out = f32  acc + bias + resid (final layer)
template <int MODE>
__global__ __launch_bounds__(256, 2) void conv_mfma(
    const unsigned short* __restrict__ xb,   // [N+1][64] bf16 (row N = zeros)
    const int* __restrict__ nbr,             // [N][K]
    const void* __restrict__ maskp,
    const int* __restrict__ flagp,
    const unsigned short* __restrict__ Wt,   // [28][64][68] bf16 padded
    const float* __restrict__ bias,          // [64]
    const float* __restrict__ resid,         // [N][64] f32 (MODE 1)
    void* __restrict__ outp,
    int N, int K)
{
    __shared__ unsigned short Wlds[2][17408];   // 2 bufs x 4 slices x 64 x 68 = 69,632B

    const int tid = threadIdx.x;
    const int wv  = tid >> 6;
    const int l   = tid & 63;
    const int lr  = l & 15;          // fragment row/col
    const int lg  = l >> 4;          // k-group 0..3 (chunk index)
    const int wavebase = blockIdx.x * 128 + wv * 32;

    // lane owns one row's neighbor offsets
    const int myrow = wavebase + (l & 31);
    const int mr = myrow < N ? myrow : N - 1;

    // ---- mask bits (uniform branch on detected dtype) ----
    unsigned mbits = 0;
    {
        const int flag = *flagp;
        long moff = (long)mr * K;
        if (flag == 1) {
            const unsigned char* mp = (const unsigned char*)maskp + moff;
#pragma unroll
            for (int k = 0; k < 27; ++k) mbits |= (mp[k] ? 1u : 0u) << k;
        } else if (flag == 0) {
            const int* mp = (const int*)maskp + moff;
#pragma unroll
            for (int k = 0; k < 27; ++k) mbits |= (mp[k] ? 1u : 0u) << k;
        } else {
            const float* mp = (const float*)maskp + moff;
#pragma unroll
            for (int k = 0; k < 27; ++k) mbits |= ((mp[k] != 0.f) ? 1u : 0u) << k;
        }
    }

    // ---- per-k byte offsets for my row (masked -> zero row N) ----
    unsigned o[28];
    {
        const int* nrow = nbr + (long)mr * K;
#pragma unroll
        for (int k = 0; k < 27; ++k) {
            unsigned g = ((mbits >> k) & 1u) ? (unsigned)nrow[k] : (unsigned)N;
            o[k] = g * 128u;
        }
        o[27] = (unsigned)N * 128u;
    }

    const int bpa0 = ((l & 32) + lr) * 4;        // owner lane of tile-0 row lr
    const int bpa1 = ((l & 32) + 16 + lr) * 4;   // owner lane of tile-1 row lr
    const unsigned chk = (unsigned)(lg << 4);    // chunk byte offset within 64B half

    const int lr68 = lr * 68 + lg * 8;           // per-lane B-frag base (u16)

    f32x4 acc[2][4] = {};
    Slot pipe[3];
    bf16x8 Bf[8];

#define STAGE(P) do { \
    const char* _srcb = (const char*)Wt + (size_t)(P) * 34816; \
    char* _dstb = (char*)(&Wlds[(P) & 1][0]); \
    _Pragma("unroll") \
    for (int _s = 0; _s < 9; ++_s) { \
        unsigned _off = (unsigned)(wv * 8704 + _s * 1024); \
        if (_off > 33792u) _off = 33792u; \
        gload_lds16((const unsigned short*)(_srcb + _off) + (l << 3), \
                    (unsigned short*)(_dstb + _off)); \
    } \
    asm volatile("" ::: "memory"); \
} while (0)

#define GISSUE(J) do { \
    unsigned _b0 = (unsigned)__builtin_amdgcn_ds_bpermute(bpa0, (int)o[J]) + chk; \
    unsigned _b1 = (unsigned)__builtin_amdgcn_ds_bpermute(bpa1, (int)o[J]) + chk; \
    Slot& _s = pipe[(J) % 3]; \
    _s.f[0] = gl16<0 >(xb, _b0); \
    _s.f[1] = gl16<64>(xb, _b0); \
    _s.f[2] = gl16<0 >(xb, _b1); \
    _s.f[3] = gl16<64>(xb, _b1); \
} while (0)

#define BLOAD(J) do { \
    const unsigned short* _wl = &Wlds[((J) >> 2) & 1][((J) & 3) * 4352]; \
    _Pragma("unroll") \
    for (int ct = 0; ct < 4; ++ct) { \
        const unsigned short* _wp = _wl + ct * 1088 + lr68; \
        Bf[ct * 2]     = ldb(_wp); \
        Bf[ct * 2 + 1] = ldb(_wp + 32); \
    } \
} while (0)

#define MFMA4(J) do { \
    Slot& _s = pipe[(J) % 3]; \
    _Pragma("unroll") \
    for (int ct = 0; ct < 4; ++ct) { \
        acc[0][ct] = __builtin_amdgcn_mfma_f32_16x16x32_bf16(_s.f[0], Bf[ct * 2],     acc[0][ct], 0, 0, 0); \
        acc[0][ct] = __builtin_amdgcn_mfma_f32_16x16x32_bf16(_s.f[1], Bf[ct * 2 + 1], acc[0][ct], 0, 0, 0); \
        acc[1][ct] = __builtin_amdgcn_mfma_f32_16x16x32_bf16(_s.f[2], Bf[ct * 2],     acc[1][ct], 0, 0, 0); \
        acc[1][ct] = __builtin_amdgcn_mfma_f32_16x16x32_bf16(_s.f[3], Bf[ct * 2 + 1], acc[1][ct], 0, 0, 0); \
    } \
} while (0)

#define FENCE() do { \
    __builtin_amdgcn_sched_barrier(0); \
    __builtin_amdgcn_s_barrier(); \
    __builtin_amdgcn_sched_barrier(0); \
} while (0)

#define STEP(J, NW) do { BLOAD(J); waitv<NW>(pipe[(J) % 3]); MFMA4(J); } while (0)

    // ---- prologue: stage phase 0, start 2 gather sets ----
    STAGE(0);
    GISSUE(0); GISSUE(1);
    asm volatile("s_waitcnt vmcnt(8)" ::: "memory");   // S_0 retired; G_0,G_1 fly
    __builtin_amdgcn_sched_barrier(0);
    __builtin_amdgcn_s_barrier();
    __builtin_amdgcn_sched_barrier(0);

    // phase 0 (k 0..3, buf 0)
    STAGE(1); GISSUE(2);  STEP(0, 17);
    GISSUE(3);  STEP(1, 17);
    GISSUE(4);  STEP(2, 8);
    GISSUE(5);  STEP(3, 8);
    FENCE();
    // phase 1 (k 4..7, buf 1)
    STAGE(2); GISSUE(6);  STEP(4, 17);
    GISSUE(7);  STEP(5, 17);
    GISSUE(8);  STEP(6, 8);
    GISSUE(9);  STEP(7, 8);
    FENCE();
    // phase 2 (k 8..11, buf 0)
    STAGE(3); GISSUE(10); STEP(8, 17);
    GISSUE(11); STEP(9, 17);
    GISSUE(12); STEP(10, 8);
    GISSUE(13); STEP(11, 8);
    FENCE();
    // phase 3 (k 12..15, buf 1)
    STAGE(4); GISSUE(14); STEP(12, 17);
    GISSUE(15); STEP(13, 17);
    GISSUE(16); STEP(14, 8);
    GISSUE(17); STEP(15, 8);
    FENCE();
    // phase 4 (k 16..19, buf 0)
    STAGE(5); GISSUE(18); STEP(16, 17);
    GISSUE(19); STEP(17, 17);
    GISSUE(20); STEP(18, 8);
    GISSUE(21); STEP(19, 8);
    FENCE();
    // phase 5 (k 20..23, buf 1)
    STAGE(6); GISSUE(22); STEP(20, 17);
    GISSUE(23); STEP(21, 17);
    GISSUE(24); STEP(22, 8);
    GISSUE(25); STEP(23, 8);
    FENCE();
    // phase 6 (k 24..27, buf 0; k=27 is the zero pad slice)
    GISSUE(26); STEP(24, 8);
    GISSUE(27); STEP(25, 8);
    STEP(26, 4);
    STEP(27, 0);

    // ---- epilogue: D col = ct*16 + lr, row = at*16 + lg*4 + rg ----
#pragma unroll
    for (int at = 0; at < 2; ++at) {
#pragma unroll
        for (int ct = 0; ct < 4; ++ct) {
            int col = ct * 16 + lr;
            float bv = bias[col];
#pragma unroll
            for (int rg = 0; rg < 4; ++rg) {
                int row = wavebase + at * 16 + lg * 4 + rg;
                if (row < N) {
                    long oo = (long)row * 64 + col;
                    float v = acc[at][ct][rg] + bv;
                    if (MODE == 0) {
                        ((unsigned short*)outp)[oo] = f2bf(v > 0.f ? v : 0.f);
                    } else {
                        ((float*)outp)[oo] = v + resid[oo];
                    }
                }
            }
        }
    }

#undef STAGE
#undef GISSUE
#undef BLOAD
#undef MFMA4
#undef FENCE
#undef STEP
}

static inline size_t align256(size_t x) { return (x + 255) & ~(size_t)255; }

extern "C" void kernel_launch(void* const* d_in, const int* in_sizes, int n_in,
                              void* d_out, int out_size, void* d_ws, size_t ws_size,
                              hipStream_t stream) {
    const float* x    = (const float*)d_in[0];
    const int*   nbr  = (const int*)d_in[1];
    const void*  mask = d_in[2];
    const float* W0   = (const float*)d_in[3];
    const float* b0   = (const float*)d_in[4];
    const float* W1   = (const float*)d_in[5];
    const float* b1   = (const float*)d_in[6];

    const int NC = in_sizes[0];      // N*64
    const int N  = NC / 64;
    const int K  = in_sizes[1] / N;  // 27
    const int KP = 28;               // padded K (slice 27 zeroed)

    char* ws = (char*)d_ws;
    size_t xb_bytes = (size_t)(NC + 64) * 2;   // +1 zero row
    size_t wt_bytes = (size_t)KP * 4352 * 2;   // padded 68-u16 rows
    size_t xb_off   = 0;
    size_t hb_off   = xb_off + align256(xb_bytes);
    size_t wt0_off  = hb_off + align256(xb_bytes);
    size_t wt1_off  = wt0_off + align256(wt_bytes);
    size_t flag_off = wt1_off + align256(wt_bytes);

    unsigned short* xb  = (unsigned short*)(ws + xb_off);
    unsigned short* hb  = (unsigned short*)(ws + hb_off);
    unsigned short* wt0 = (unsigned short*)(ws + wt0_off);
    unsigned short* wt1 = (unsigned short*)(ws + wt1_off);
    int* flag           = (int*)(ws + flag_off);

    int n4 = NC / 4;
    int n4tot = n4 + 16;             // + zero pad row (16 u16x4 = 64 ch)
    prep_x<<<(n4tot + 255) / 256, 256, 0, stream>>>((const f32x4*)x, (u16x4*)xb, n4, n4tot);
    zero_row<<<1, 64, 0, stream>>>(hb, (long)NC);
    prep_w<<<KP, 256, 0, stream>>>(W0, wt0, K);
    prep_w<<<KP, 256, 0, stream>>>(W1, wt1, K);
    detect_mask<<<1, 1024, 0, stream>>>((const unsigned int*)mask, flag);

    int nblocks = (N + 127) / 128;
    conv_mfma<0><<<nblocks, 256, 0, stream>>>(xb, nbr, mask, flag, wt0, b0, nullptr, hb, N, K);
    conv_mfma<1><<<nblocks, 256, 0, stream>>>(hb, nbr, mask, flag, wt1, b1, x, d_out, N, K);
}

// Round 6
// 357.337 us; speedup vs baseline: 3.3504x; 1.0336x over previous
//
#include <hip/hip_runtime.h>
#include <hip/hip_bf16.h>
#include <stdint.h>

typedef __bf16 bf16x8 __attribute__((ext_vector_type(8)));
typedef float f32x4 __attribute__((ext_vector_type(4)));
typedef unsigned short u16x4 __attribute__((ext_vector_type(4)));

__device__ __forceinline__ unsigned short f2bf(float f) {
    union { float f; uint32_t u; } v; v.f = f;
    uint32_t u = v.u;
    return (unsigned short)((u + 0x7fffu + ((u >> 16) & 1u)) >> 16);
}

// ---- prep: f32 -> bf16 feature conversion (x4); tail zeroes the pad row ----
__global__ __launch_bounds__(256) void prep_x(const f32x4* __restrict__ x,
                                              u16x4* __restrict__ xb, int n4, int n4tot) {
    int t = blockIdx.x * 256 + threadIdx.x;
    if (t < n4) {
        f32x4 v = x[t];
        u16x4 o;
        o.x = f2bf(v.x); o.y = f2bf(v.y); o.z = f2bf(v.z); o.w = f2bf(v.w);
        xb[t] = o;
    } else if (t < n4tot) {
        u16x4 z = {0, 0, 0, 0};
        xb[t] = z;                       // zero row at index N (masked-gather target)
    }
}

// ---- zero one 64-ch row (pad row of the hidden buffer) ----
__global__ void zero_row(unsigned short* __restrict__ p, long off) {
    p[off + threadIdx.x] = 0;
}

// ---- prep: W[k][ci][co] f32 -> Wt[k][co][ci] bf16, rows PADDED to 72 u16 ----
// 72-u16 (144B) row stride: 16B-aligned for every row => ds_read_b128 legal,
// and dword-bank pattern 4*(lr+lg) mod 32 is uniform => conflict-free.
__global__ __launch_bounds__(256) void prep_w(const float* __restrict__ W,
                                              unsigned short* __restrict__ Wt, int K) {
    int k = blockIdx.x;
    unsigned short* Wtk = Wt + (size_t)k * 4608;      // 64 rows * 72
    const float* Wk = W + (size_t)k * 4096;
    for (int j = threadIdx.x; j < 4608; j += 256) {
        int co = j / 72, ci = j % 72;
        unsigned short v = 0;
        if (k < K && ci < 64) v = f2bf(Wk[ci * 64 + co]);   // W[k][ci][co]
        Wtk[j] = v;
    }
}

// ---- detect mask element width: 0=int32, 1=bytes(bool), 2=float32 ----
__global__ void detect_mask(const unsigned int* __restrict__ m, int* __restrict__ flag) {
    __shared__ int s_not_int, s_not_f32;
    if (threadIdx.x == 0) { s_not_int = 0; s_not_f32 = 0; }
    __syncthreads();
    unsigned int w = m[threadIdx.x];          // first 4KB: safe for all widths
    if (w > 1u) s_not_int = 1;                // benign race
    if (w != 0u && w != 0x3f800000u) s_not_f32 = 1;
    __syncthreads();
    if (threadIdx.x == 0) *flag = s_not_int ? (s_not_f32 ? 1 : 2) : 0;
}

// ---- asm 16B gather load (async; counted vmcnt domain) ----
template <int IOFF>
__device__ __forceinline__ bf16x8 gl16(const unsigned short* base, unsigned voff) {
    bf16x8 r;
    asm volatile("global_load_dwordx4 %0, %1, %2 offset:%c3"
                 : "=v"(r) : "v"(voff), "s"(base), "i"(IOFF));
    return r;
}

struct Slot { bf16x8 f[8]; };   // [at*2 + slice]: 4 row-tiles x 2 k-slices

// counted wait tying the slot registers: consuming MFMAs can't be hoisted above.
template <int NW>
__device__ __forceinline__ void waitv(Slot& s) {
    asm volatile("s_waitcnt vmcnt(%c8)"
                 : "+v"(s.f[0]), "+v"(s.f[1]), "+v"(s.f[2]), "+v"(s.f[3]),
                   "+v"(s.f[4]), "+v"(s.f[5]), "+v"(s.f[6]), "+v"(s.f[7])
                 : "i"(NW));
    __builtin_amdgcn_sched_barrier(0);
}

__device__ __forceinline__ void gload_lds16(const unsigned short* g, unsigned short* l) {
    __builtin_amdgcn_global_load_lds(
        (const __attribute__((address_space(1))) void*)(const void*)g,
        (__attribute__((address_space(3))) void*)(void*)l, 16, 0, 0);
}

// ---- main sparse conv ----
// 4 waves x 64 rows = 256 rows/block, mfma 16x16x32, 4 row-tiles per wave.
// A gathered straight into fragments (16 rows x 4-lane-coalesced 64B / inst),
// W staged in LDS (72-u16 padded rows, ds_read_b128). 2-slot gather pipeline
// with counted vmcnt; W double-buffered 4 slices/phase.
// MODE 0: out = bf16 relu(acc + bias)   (hidden layer)
// MODE 1: out = f32  acc + bias + resid (final layer)
template <int MODE>
__global__ __launch_bounds__(256, 2) void conv_mfma(
    const unsigned short* __restrict__ xb,   // [N+1][64] bf16 (row N = zeros)
    const int* __restrict__ nbr,             // [N][K]
    const void* __restrict__ maskp,
    const int* __restrict__ flagp,
    const unsigned short* __restrict__ Wt,   // [28][64][72] bf16 padded
    const float* __restrict__ bias,          // [64]
    const float* __restrict__ resid,         // [N][64] f32 (MODE 1)
    void* __restrict__ outp,
    int N, int K)
{
    __shared__ unsigned short Wlds[2][18432];   // 2 bufs x 4 slices x 64 x 72 = 73,728B

    const int tid = threadIdx.x;
    const int wv  = tid >> 6;
    const int l   = tid & 63;
    const int lr  = l & 15;          // fragment row/col
    const int lg  = l >> 4;          // k-chunk 0..3
    const int wavebase = blockIdx.x * 256 + wv * 64;

    // each lane owns exactly one row's neighbor offsets
    const int myrow = wavebase + l;
    const int mr = myrow < N ? myrow : N - 1;

    // ---- mask bits (uniform branch on detected dtype) ----
    unsigned mbits = 0;
    {
        const int flag = *flagp;
        long moff = (long)mr * K;
        if (flag == 1) {
            const unsigned char* mp = (const unsigned char*)maskp + moff;
#pragma unroll
            for (int k = 0; k < 27; ++k) mbits |= (mp[k] ? 1u : 0u) << k;
        } else if (flag == 0) {
            const int* mp = (const int*)maskp + moff;
#pragma unroll
            for (int k = 0; k < 27; ++k) mbits |= (mp[k] ? 1u : 0u) << k;
        } else {
            const float* mp = (const float*)maskp + moff;
#pragma unroll
            for (int k = 0; k < 27; ++k) mbits |= ((mp[k] != 0.f) ? 1u : 0u) << k;
        }
    }

    // ---- per-k byte offsets for my row (masked -> zero row N) ----
    unsigned o[28];
    {
        const int* nrow = nbr + (long)mr * K;
#pragma unroll
        for (int k = 0; k < 27; ++k) {
            unsigned g = ((mbits >> k) & 1u) ? (unsigned)nrow[k] : (unsigned)N;
            o[k] = g * 128u;
        }
        o[27] = (unsigned)N * 128u;
    }

    // owner-lane bpermute addresses for the 4 row-tiles
    const int bpa0 = (0 * 16 + lr) * 4;
    const int bpa1 = (1 * 16 + lr) * 4;
    const int bpa2 = (2 * 16 + lr) * 4;
    const int bpa3 = (3 * 16 + lr) * 4;
    const unsigned chk = (unsigned)(lg << 4);    // chunk byte offset within 64B half

    const int lrw = lr * 72 + lg * 8;            // per-lane B-frag base (u16, within ct row-group)

    f32x4 acc[4][4] = {};
    Slot pipe[2];
    bf16x8 Bf[8];

#define STAGE(P) do { \
    const unsigned short* _src = Wt + (size_t)(P) * 18432 + wv * 4608 + (l << 3); \
    unsigned short* _dst = &Wlds[(P) & 1][wv * 4608]; \
    _Pragma("unroll") \
    for (int _s = 0; _s < 9; ++_s) \
        gload_lds16(_src + _s * 512, _dst + _s * 512); \
    asm volatile("" ::: "memory"); \
} while (0)

#define GISSUE(J) do { \
    unsigned _b0 = (unsigned)__builtin_amdgcn_ds_bpermute(bpa0, (int)o[J]) + chk; \
    unsigned _b1 = (unsigned)__builtin_amdgcn_ds_bpermute(bpa1, (int)o[J]) + chk; \
    unsigned _b2 = (unsigned)__builtin_amdgcn_ds_bpermute(bpa2, (int)o[J]) + chk; \
    unsigned _b3 = (unsigned)__builtin_amdgcn_ds_bpermute(bpa3, (int)o[J]) + chk; \
    Slot& _s = pipe[(J) & 1]; \
    _s.f[0] = gl16<0 >(xb, _b0); _s.f[1] = gl16<64>(xb, _b0); \
    _s.f[2] = gl16<0 >(xb, _b1); _s.f[3] = gl16<64>(xb, _b1); \
    _s.f[4] = gl16<0 >(xb, _b2); _s.f[5] = gl16<64>(xb, _b2); \
    _s.f[6] = gl16<0 >(xb, _b3); _s.f[7] = gl16<64>(xb, _b3); \
} while (0)

#define BLOAD(J) do { \
    const unsigned short* _wl = &Wlds[((J) >> 2) & 1][((J) & 3) * 4608]; \
    _Pragma("unroll") \
    for (int ct = 0; ct < 4; ++ct) { \
        const unsigned short* _wp = _wl + ct * 1152 + lrw; \
        Bf[ct * 2]     = *(const bf16x8*)(_wp); \
        Bf[ct * 2 + 1] = *(const bf16x8*)(_wp + 32); \
    } \
} while (0)

#define MFMA16(J) do { \
    Slot& _s = pipe[(J) & 1]; \
    _Pragma("unroll") \
    for (int ct = 0; ct < 4; ++ct) { \
        _Pragma("unroll") \
        for (int at = 0; at < 4; ++at) { \
            acc[at][ct] = __builtin_amdgcn_mfma_f32_16x16x32_bf16(_s.f[at * 2],     Bf[ct * 2],     acc[at][ct], 0, 0, 0); \
            acc[at][ct] = __builtin_amdgcn_mfma_f32_16x16x32_bf16(_s.f[at * 2 + 1], Bf[ct * 2 + 1], acc[at][ct], 0, 0, 0); \
        } \
    } \
} while (0)

#define FENCE() do { \
    asm volatile("s_waitcnt vmcnt(16)" ::: "memory"); \
    __builtin_amdgcn_sched_barrier(0); \
    __builtin_amdgcn_s_barrier(); \
    __builtin_amdgcn_sched_barrier(0); \
} while (0)

#define STEP(J, NW) do { BLOAD(J); waitv<NW>(pipe[(J) & 1]); MFMA16(J); } while (0)

    // ---- prologue: stage phase 0, start 2 gather sets ----
    STAGE(0);
    GISSUE(0); GISSUE(1);
    asm volatile("s_waitcnt vmcnt(16)" ::: "memory");   // STAGE(0) retired; G0,G1 fly
    __builtin_amdgcn_sched_barrier(0);
    __builtin_amdgcn_s_barrier();
    __builtin_amdgcn_sched_barrier(0);

    // phase 0 (k 0..3, buf 0)
    STAGE(1); STEP(0, 17); GISSUE(2);
    STEP(1, 17); GISSUE(3);
    STEP(2, 8);  GISSUE(4);
    STEP(3, 8);  GISSUE(5);
    FENCE();
    // phase 1 (k 4..7, buf 1)
    STAGE(2); STEP(4, 17); GISSUE(6);
    STEP(5, 17); GISSUE(7);
    STEP(6, 8);  GISSUE(8);
    STEP(7, 8);  GISSUE(9);
    FENCE();
    // phase 2 (k 8..11, buf 0)
    STAGE(3); STEP(8, 17); GISSUE(10);
    STEP(9, 17);  GISSUE(11);
    STEP(10, 8);  GISSUE(12);
    STEP(11, 8);  GISSUE(13);
    FENCE();
    // phase 3 (k 12..15, buf 1)
    STAGE(4); STEP(12, 17); GISSUE(14);
    STEP(13, 17); GISSUE(15);
    STEP(14, 8);  GISSUE(16);
    STEP(15, 8);  GISSUE(17);
    FENCE();
    // phase 4 (k 16..19, buf 0)
    STAGE(5); STEP(16, 17); GISSUE(18);
    STEP(17, 17); GISSUE(19);
    STEP(18, 8);  GISSUE(20);
    STEP(19, 8);  GISSUE(21);
    FENCE();
    // phase 5 (k 20..23, buf 1)
    STAGE(6); STEP(20, 17); GISSUE(22);
    STEP(21, 17); GISSUE(23);
    STEP(22, 8);  GISSUE(24);
    STEP(23, 8);  GISSUE(25);
    FENCE();
    // phase 6 (k 24..27, buf 0; k=27 is the zero pad slice)
    STEP(24, 8);  GISSUE(26);
    STEP(25, 8);  GISSUE(27);
    STEP(26, 8);
    STEP(27, 0);

    // ---- epilogue: D col = ct*16 + lr, row = wavebase + at*16 + lg*4 + rg ----
#pragma unroll
    for (int at = 0; at < 4; ++at) {
#pragma unroll
        for (int ct = 0; ct < 4; ++ct) {
            int col = ct * 16 + lr;
            float bv = bias[col];
#pragma unroll
            for (int rg = 0; rg < 4; ++rg) {
                int row = wavebase + at * 16 + lg * 4 + rg;
                if (row < N) {
                    long oo = (long)row * 64 + col;
                    float v = acc[at][ct][rg] + bv;
                    if (MODE == 0) {
                        ((unsigned short*)outp)[oo] = f2bf(v > 0.f ? v : 0.f);
                    } else {
                        ((float*)outp)[oo] = v + resid[oo];
                    }
                }
            }
        }
    }

#undef STAGE
#undef GISSUE
#undef BLOAD
#undef MFMA16
#undef FENCE
#undef STEP
}

static inline size_t align256(size_t x) { return (x + 255) & ~(size_t)255; }

extern "C" void kernel_launch(void* const* d_in, const int* in_sizes, int n_in,
                              void* d_out, int out_size, void* d_ws, size_t ws_size,
                              hipStream_t stream) {
    const float* x    = (const float*)d_in[0];
    const int*   nbr  = (const int*)d_in[1];
    const void*  mask = d_in[2];
    const float* W0   = (const float*)d_in[3];
    const float* b0   = (const float*)d_in[4];
    const float* W1   = (const float*)d_in[5];
    const float* b1   = (const float*)d_in[6];

    const int NC = in_sizes[0];      // N*64
    const int N  = NC / 64;
    const int K  = in_sizes[1] / N;  // 27
    const int KP = 28;               // padded K (slice 27 zeroed)

    char* ws = (char*)d_ws;
    size_t xb_bytes = (size_t)(NC + 64) * 2;   // +1 zero row
    size_t wt_bytes = (size_t)KP * 4608 * 2;   // padded 72-u16 rows
    size_t xb_off   = 0;
    size_t hb_off   = xb_off + align256(xb_bytes);
    size_t wt0_off  = hb_off + align256(xb_bytes);
    size_t wt1_off  = wt0_off + align256(wt_bytes);
    size_t flag_off = wt1_off + align256(wt_bytes);

    unsigned short* xb  = (unsigned short*)(ws + xb_off);
    unsigned short* hb  = (unsigned short*)(ws + hb_off);
    unsigned short* wt0 = (unsigned short*)(ws + wt0_off);
    unsigned short* wt1 = (unsigned short*)(ws + wt1_off);
    int* flag           = (int*)(ws + flag_off);

    int n4 = NC / 4;
    int n4tot = n4 + 16;             // + zero pad row (16 u16x4 = 64 ch)
    prep_x<<<(n4tot + 255) / 256, 256, 0, stream>>>((const f32x4*)x, (u16x4*)xb, n4, n4tot);
    zero_row<<<1, 64, 0, stream>>>(hb, (long)NC);
    prep_w<<<KP, 256, 0, stream>>>(W0, wt0, K);
    prep_w<<<KP, 256, 0, stream>>>(W1, wt1, K);
    detect_mask<<<1, 1024, 0, stream>>>((const unsigned int*)mask, flag);

    int nblocks = (N + 255) / 256;
    conv_mfma<0><<<nblocks, 256, 0, stream>>>(xb, nbr, mask, flag, wt0, b0, nullptr, hb, N, K);
    conv_mfma<1><<<nblocks, 256, 0, stream>>>(hb, nbr, mask, flag, wt1, b1, x, d_out, N, K);
}

// Round 8
// 339.392 us; speedup vs baseline: 3.5276x; 1.0529x over previous
//
#include <hip/hip_runtime.h>
#include <hip/hip_bf16.h>
#include <stdint.h>

typedef __bf16 bf16x8 __attribute__((ext_vector_type(8)));
typedef float f32x4 __attribute__((ext_vector_type(4)));
typedef unsigned short u16x4 __attribute__((ext_vector_type(4)));

__device__ __forceinline__ unsigned short f2bf(float f) {
    union { float f; uint32_t u; } v; v.f = f;
    uint32_t u = v.u;
    return (unsigned short)((u + 0x7fffu + ((u >> 16) & 1u)) >> 16);
}

__device__ __forceinline__ float bf2f(unsigned short b) {
    union { uint32_t u; float f; } v; v.u = ((uint32_t)b) << 16;
    return v.f;
}

// ---- prep: f32 -> bf16 feature conversion (x4); tail zeroes the pad row ----
__global__ __launch_bounds__(256) void prep_x(const f32x4* __restrict__ x,
                                              u16x4* __restrict__ xb, int n4, int n4tot) {
    int t = blockIdx.x * 256 + threadIdx.x;
    if (t < n4) {
        f32x4 v = x[t];
        u16x4 o;
        o.x = f2bf(v.x); o.y = f2bf(v.y); o.z = f2bf(v.z); o.w = f2bf(v.w);
        xb[t] = o;
    } else if (t < n4tot) {
        u16x4 z = {0, 0, 0, 0};
        xb[t] = z;                       // zero row at index N (masked-gather target)
    }
}

// ---- zero one 64-ch row (pad row of the hidden buffer) ----
__global__ void zero_row(unsigned short* __restrict__ p, long off) {
    p[off + threadIdx.x] = 0;
}

// ---- prep: W[k][ci][co] f32 -> FRAGMENT-ORDERED Wf[k][4096] bf16 ----
// u16 index = (ct*2+h)*512 + l*8 + j  <->  W[ci][co], ci = h*32+(l>>4)*8+j,
// co = ct*16+(l&15). LDS reads become lane-linear (base + lane*16B):
// bank-conflict-free, and staging is a plain linear copy.
__global__ __launch_bounds__(256) void prep_w(const float* __restrict__ W,
                                              unsigned short* __restrict__ Wf, int K) {
    int k = blockIdx.x;
    unsigned short* Wfk = Wf + (size_t)k * 4096;
    const float* Wk = W + (size_t)k * 4096;
    for (int idx = threadIdx.x; idx < 4096; idx += 256) {
        int j   = idx & 7;
        int l   = (idx >> 3) & 63;
        int c2h = idx >> 9;               // ct*2 + h
        int ct  = c2h >> 1, h = c2h & 1;
        int ci  = h * 32 + (l >> 4) * 8 + j;
        int co  = ct * 16 + (l & 15);
        Wfk[idx] = (k < K) ? f2bf(Wk[ci * 64 + co]) : (unsigned short)0;
    }
}

// ---- detect mask element width: 0=int32, 1=bytes(bool), 2=float32 ----
__global__ void detect_mask(const unsigned int* __restrict__ m, int* __restrict__ flag) {
    __shared__ int s_not_int, s_not_f32;
    if (threadIdx.x == 0) { s_not_int = 0; s_not_f32 = 0; }
    __syncthreads();
    unsigned int w = m[threadIdx.x];          // first 4KB: safe for all widths
    if (w > 1u) s_not_int = 1;                // benign race
    if (w != 0u && w != 0x3f800000u) s_not_f32 = 1;
    __syncthreads();
    if (threadIdx.x == 0) *flag = s_not_int ? (s_not_f32 ? 1 : 2) : 0;
}

// ---- asm 16B gather load (async; counted vmcnt domain) ----
template <int IOFF>
__device__ __forceinline__ bf16x8 gl16(const unsigned short* base, unsigned voff) {
    bf16x8 r;
    asm volatile("global_load_dwordx4 %0, %1, %2 offset:%c3"
                 : "=v"(r) : "v"(voff), "s"(base), "i"(IOFF));
    return r;
}

struct Slot { bf16x8 f[8]; };   // [at*2 + half]: 4 row-tiles x 2 k-halves

// counted wait tying the slot registers: consuming MFMAs can't be hoisted above.
template <int NW>
__device__ __forceinline__ void waitv(Slot& s) {
    asm volatile("s_waitcnt vmcnt(%c8)"
                 : "+v"(s.f[0]), "+v"(s.f[1]), "+v"(s.f[2]), "+v"(s.f[3]),
                   "+v"(s.f[4]), "+v"(s.f[5]), "+v"(s.f[6]), "+v"(s.f[7])
                 : "i"(NW));
    __builtin_amdgcn_sched_barrier(0);
}

__device__ __forceinline__ void gload_lds16(const unsigned short* g, unsigned short* l) {
    __builtin_amdgcn_global_load_lds(
        (const __attribute__((address_space(1))) void*)(const void*)g,
        (__attribute__((address_space(3))) void*)(void*)l, 16, 0, 0);
}

// ---- main sparse conv ----
// 4 waves x 64 rows = 256 rows/block, mfma 16x16x32, 4 row-tiles per wave.
// A gathered straight into fragments; W staged in LDS (fragment-ordered,
// lane-linear reads) double-buffered in 2-slice phases (32,768B LDS ->
// up to 4 blocks/CU at <=128 VGPR). Counted vmcnt keeps gathers in flight.
// MODE 0: out = bf16 relu(acc + bias)   (hidden layer)
// MODE 1: out = f32  acc + bias + bf2f(residb) (final layer)
template <int MODE>
__global__ __launch_bounds__(256, 2) void conv_mfma(
    const unsigned short* __restrict__ xb,   // [N+1][64] bf16 (row N = zeros)
    const int* __restrict__ nbr,             // [N][K]
    const void* __restrict__ maskp,
    const int* __restrict__ flagp,
    const unsigned short* __restrict__ Wf,   // [28][4096] bf16 fragment-ordered
    const float* __restrict__ bias,          // [64]
    const unsigned short* __restrict__ residb, // [N][64] bf16 (MODE 1: = xb)
    void* __restrict__ outp,
    int N, int K)
{
    __shared__ unsigned short Wlds[16384];   // 2 bufs x 2 slices x 4096 = 32,768B

    const int tid = threadIdx.x;
    const int wv  = tid >> 6;
    const int l   = tid & 63;
    const int lr  = l & 15;          // fragment row/col
    const int lg  = l >> 4;          // k-chunk 0..3
    const int wavebase = blockIdx.x * 256 + wv * 64;

    // each lane owns exactly one row's neighbor offsets
    const int myrow = wavebase + l;
    const int mr = myrow < N ? myrow : N - 1;

    // ---- mask bits (uniform branch on detected dtype) ----
    unsigned mbits = 0;
    {
        const int flag = *flagp;
        long moff = (long)mr * K;
        if (flag == 1) {
            const unsigned char* mp = (const unsigned char*)maskp + moff;
#pragma unroll
            for (int k = 0; k < 27; ++k) mbits |= (mp[k] ? 1u : 0u) << k;
        } else if (flag == 0) {
            const int* mp = (const int*)maskp + moff;
#pragma unroll
            for (int k = 0; k < 27; ++k) mbits |= (mp[k] ? 1u : 0u) << k;
        } else {
            const float* mp = (const float*)maskp + moff;
#pragma unroll
            for (int k = 0; k < 27; ++k) mbits |= ((mp[k] != 0.f) ? 1u : 0u) << k;
        }
    }

    // ---- per-k byte offsets for my row (masked -> zero row N) ----
    unsigned o[28];
    {
        const int* nrow = nbr + (long)mr * K;
#pragma unroll
        for (int k = 0; k < 27; ++k) {
            unsigned g = ((mbits >> k) & 1u) ? (unsigned)nrow[k] : (unsigned)N;
            o[k] = g * 128u;
        }
        o[27] = (unsigned)N * 128u;
    }

    // owner-lane bpermute addresses for the 4 row-tiles
    const int bpa0 = (0 * 16 + lr) * 4;
    const int bpa1 = (1 * 16 + lr) * 4;
    const int bpa2 = (2 * 16 + lr) * 4;
    const int bpa3 = (3 * 16 + lr) * 4;
    const unsigned chk = (unsigned)(lg << 4);    // chunk byte offset within 64B half

    f32x4 acc[4][4] = {};
    Slot pipe[2];
    bf16x8 Bf[8];

// stage 2 k-slices (16KB) for phase P into buffer P&1.
// dst is WAVE-UNIFORM (wv-based); src is per-lane (tid-contiguous 16B):
// HW writes dst + lane*16B, matching src lane l exactly (r6-proven pattern).
#define STAGE(P) do { \
    const unsigned short* _src = Wf + (size_t)(P) * 8192 + wv * 2048 + (l << 3); \
    unsigned short* _dst = &Wlds[((P) & 1) * 8192 + wv * 2048]; \
    _Pragma("unroll") \
    for (int _s = 0; _s < 4; ++_s) \
        gload_lds16(_src + _s * 512, _dst + _s * 512); \
    asm volatile("" ::: "memory"); \
} while (0)

#define GISSUE(J) do { \
    unsigned _b0 = (unsigned)__builtin_amdgcn_ds_bpermute(bpa0, (int)o[J]) + chk; \
    unsigned _b1 = (unsigned)__builtin_amdgcn_ds_bpermute(bpa1, (int)o[J]) + chk; \
    unsigned _b2 = (unsigned)__builtin_amdgcn_ds_bpermute(bpa2, (int)o[J]) + chk; \
    unsigned _b3 = (unsigned)__builtin_amdgcn_ds_bpermute(bpa3, (int)o[J]) + chk; \
    Slot& _s = pipe[(J) & 1]; \
    _s.f[0] = gl16<0 >(xb, _b0); _s.f[1] = gl16<64>(xb, _b0); \
    _s.f[2] = gl16<0 >(xb, _b1); _s.f[3] = gl16<64>(xb, _b1); \
    _s.f[4] = gl16<0 >(xb, _b2); _s.f[5] = gl16<64>(xb, _b2); \
    _s.f[6] = gl16<0 >(xb, _b3); _s.f[7] = gl16<64>(xb, _b3); \
} while (0)

// lane-linear fragment read: buf=(J>>1)&1, slice=J&1; conflict-free
#define BLOAD(J) do { \
    const unsigned short* _wl = &Wlds[(((J) >> 1) & 1) * 8192 + ((J) & 1) * 4096]; \
    _Pragma("unroll") \
    for (int _c = 0; _c < 8; ++_c) \
        Bf[_c] = *(const bf16x8*)(_wl + _c * 512 + l * 8); \
} while (0)

#define MFMA16(J) do { \
    Slot& _s = pipe[(J) & 1]; \
    _Pragma("unroll") \
    for (int ct = 0; ct < 4; ++ct) { \
        _Pragma("unroll") \
        for (int at = 0; at < 4; ++at) { \
            acc[at][ct] = __builtin_amdgcn_mfma_f32_16x16x32_bf16(_s.f[at * 2],     Bf[ct * 2],     acc[at][ct], 0, 0, 0); \
            acc[at][ct] = __builtin_amdgcn_mfma_f32_16x16x32_bf16(_s.f[at * 2 + 1], Bf[ct * 2 + 1], acc[at][ct], 0, 0, 0); \
        } \
    } \
} while (0)

#define FENCE() do { \
    asm volatile("s_waitcnt vmcnt(16)" ::: "memory"); \
    __builtin_amdgcn_sched_barrier(0); \
    __builtin_amdgcn_s_barrier(); \
    __builtin_amdgcn_sched_barrier(0); \
} while (0)

#define STEP(J, NW) do { BLOAD(J); waitv<NW>(pipe[(J) & 1]); MFMA16(J); } while (0)

// one steady-state phase: stage next buffer, 2 compute steps, 2 gather issues
#define PHASE(PH1, K0) do { \
    STAGE(PH1); \
    STEP(K0, 12);       GISSUE((K0) + 2); \
    STEP((K0) + 1, 12); GISSUE((K0) + 3); \
    FENCE(); \
} while (0)

    // ---- prologue: stage phase 0, start 2 gather sets ----
    STAGE(0);
    GISSUE(0); GISSUE(1);
    asm volatile("s_waitcnt vmcnt(16)" ::: "memory");   // STAGE(0) retired; G0,G1 fly
    __builtin_amdgcn_sched_barrier(0);
    __builtin_amdgcn_s_barrier();
    __builtin_amdgcn_sched_barrier(0);

    PHASE(1, 0);   PHASE(2, 2);   PHASE(3, 4);   PHASE(4, 6);
    PHASE(5, 8);   PHASE(6, 10);  PHASE(7, 12);  PHASE(8, 14);
    PHASE(9, 16);  PHASE(10, 18); PHASE(11, 20); PHASE(12, 22);
    PHASE(13, 24);
    // tail (k 26,27; buf 1; k=27 is the zero pad slice)
    STEP(26, 8);
    STEP(27, 0);

    // ---- epilogue: D col = ct*16 + lr, row = wavebase + at*16 + lg*4 + rg ----
#pragma unroll
    for (int at = 0; at < 4; ++at) {
#pragma unroll
        for (int ct = 0; ct < 4; ++ct) {
            int col = ct * 16 + lr;
            float bv = bias[col];
#pragma unroll
            for (int rg = 0; rg < 4; ++rg) {
                int row = wavebase + at * 16 + lg * 4 + rg;
                if (row < N) {
                    long oo = (long)row * 64 + col;
                    float v = acc[at][ct][rg] + bv;
                    if (MODE == 0) {
                        ((unsigned short*)outp)[oo] = f2bf(v > 0.f ? v : 0.f);
                    } else {
                        ((float*)outp)[oo] = v + bf2f(residb[oo]);
                    }
                }
            }
        }
    }

#undef STAGE
#undef GISSUE
#undef BLOAD
#undef MFMA16
#undef FENCE
#undef STEP
#undef PHASE
}

static inline size_t align256(size_t x) { return (x + 255) & ~(size_t)255; }

extern "C" void kernel_launch(void* const* d_in, const int* in_sizes, int n_in,
                              void* d_out, int out_size, void* d_ws, size_t ws_size,
                              hipStream_t stream) {
    const float* x    = (const float*)d_in[0];
    const int*   nbr  = (const int*)d_in[1];
    const void*  mask = d_in[2];
    const float* W0   = (const float*)d_in[3];
    const float* b0   = (const float*)d_in[4];
    const float* W1   = (const float*)d_in[5];
    const float* b1   = (const float*)d_in[6];

    const int NC = in_sizes[0];      // N*64
    const int N  = NC / 64;
    const int K  = in_sizes[1] / N;  // 27
    const int KP = 28;               // padded K (slice 27 zeroed)

    char* ws = (char*)d_ws;
    size_t xb_bytes = (size_t)(NC + 64) * 2;   // +1 zero row
    size_t wt_bytes = (size_t)KP * 4096 * 2;   // fragment-ordered
    size_t xb_off   = 0;
    size_t hb_off   = xb_off + align256(xb_bytes);
    size_t wt0_off  = hb_off + align256(xb_bytes);
    size_t wt1_off  = wt0_off + align256(wt_bytes);
    size_t flag_off = wt1_off + align256(wt_bytes);

    unsigned short* xb  = (unsigned short*)(ws + xb_off);
    unsigned short* hb  = (unsigned short*)(ws + hb_off);
    unsigned short* wf0 = (unsigned short*)(ws + wt0_off);
    unsigned short* wf1 = (unsigned short*)(ws + wt1_off);
    int* flag           = (int*)(ws + flag_off);

    int n4 = NC / 4;
    int n4tot = n4 + 16;             // + zero pad row (16 u16x4 = 64 ch)
    prep_x<<<(n4tot + 255) / 256, 256, 0, stream>>>((const f32x4*)x, (u16x4*)xb, n4, n4tot);
    zero_row<<<1, 64, 0, stream>>>(hb, (long)NC);
    prep_w<<<KP, 256, 0, stream>>>(W0, wf0, K);
    prep_w<<<KP, 256, 0, stream>>>(W1, wf1, K);
    detect_mask<<<1, 1024, 0, stream>>>((const unsigned int*)mask, flag);

    int nblocks = (N + 255) / 256;
    conv_mfma<0><<<nblocks, 256, 0, stream>>>(xb, nbr, mask, flag, wf0, b0, nullptr, hb, N, K);
    conv_mfma<1><<<nblocks, 256, 0, stream>>>(hb, nbr, mask, flag, wf1, b1, xb, d_out, N, K);
}